// Round 5
// baseline (3390.376 us; speedup 1.0000x reference)
//
#include <hip/hip_runtime.h>
#include <stdint.h>

#define N_ROWS  8192   // B*S = 4*2048
#define DIM     256
#define K_CODES 8192
#define SPLITK  8
#define KS      1024          // codes per split
#define ROWS_B  64            // rows per block
#define KT_CODES 256          // codes per kt iteration (64 per wave)
#define LSLOTS  24            // per-row append slots in LDS
#define GSLOTS  8             // per-row-split survivor slots (64/row = 1 u64/lane)
// acc(dot) margin >= dist-grid/2 (1.5e-5) + 2*bf16 dot err max (~2.2e-5) + cnorm (2e-6)
#define MARGIN_ACC 1.0e-4f

typedef unsigned long long u64;
typedef unsigned short u16;
typedef short s16x8 __attribute__((ext_vector_type(8)));   // 8 bf16 = 4 VGPR
typedef float f32x4 __attribute__((ext_vector_type(4)));

__device__ __forceinline__ u64 u64min(u64 a, u64 b) { return a < b ? a : b; }

__device__ __forceinline__ u16 f2bf(float f) {   // RNE, no NaNs here
    unsigned u = __float_as_uint(f);
    u += 0x7fffu + ((u >> 16) & 1u);
    return (u16)(u >> 16);
}

__device__ __forceinline__ void gld16(void* lds, const void* g) {
    __builtin_amdgcn_global_load_lds(
        (const __attribute__((address_space(1))) unsigned int*)g,
        (__attribute__((address_space(3))) unsigned int*)lds, 16, 0, 0);
}

// exact fp32 dot, the R2-proven association (sequential fmaf d=0..255)
__device__ __forceinline__ float exact_dot(const float* __restrict__ xr,
                                           const float* __restrict__ cr) {
    float acc = 0.0f;
#pragma unroll 8
    for (int d = 0; d < DIM; d++)
        acc = __builtin_fmaf(xr[d], cr[d], acc);
    return acc;
}

// ---------------------------------------------------------------- kernel A
// Fused: bf16 conversion of z_e & cb + row norms. One wave per row.
__global__ __launch_bounds__(256) void vq_prep(const float* __restrict__ z_e,
                                               const float* __restrict__ cb,
                                               u16* __restrict__ zb,
                                               u16* __restrict__ cbb,
                                               float* __restrict__ xnorm,
                                               float* __restrict__ cnorm) {
    int wid  = (blockIdx.x * 256 + threadIdx.x) >> 6;
    int lane = threadIdx.x & 63;
    const float* src; u16* d16; float* dn;
    if (wid < N_ROWS) { src = z_e + (size_t)wid * DIM; d16 = zb + (size_t)wid * DIM; dn = xnorm + wid; }
    else              { int k = wid - N_ROWS;
                        src = cb  + (size_t)k   * DIM; d16 = cbb + (size_t)k * DIM; dn = cnorm + k; }
    float4 v = *(const float4*)(src + lane * 4);
    ushort4 h;
    h.x = f2bf(v.x); h.y = f2bf(v.y); h.z = f2bf(v.z); h.w = f2bf(v.w);
    *(ushort4*)(d16 + lane * 4) = h;
    float s = (v.x * v.x + v.y * v.y) + (v.z * v.z + v.w * v.w);
#pragma unroll
    for (int off = 1; off < 64; off <<= 1)
        s += __shfl_xor(s, off, 64);
    if (lane == 0) *dn = s;
}

// ---------------------------------------------------------------- kernel B
// Barrier-free-K-loop MFMA dot GEMM + margin-candidate emission.
// Block = 64 rows x 1024 codes (one split). X-tile resident in LDS (32 KB,
// XOR-swizzled 16B chunks: pos = chunk ^ (row&7) -> ds_read_b128 2-way=free).
// B-frags loaded per-lane from global (L2-resident split) -> NO K-loop barriers.
// Wave w covers codes [kt*256 + w*64, +64): 4 row-tiles x 4 code-tiles 16x16x32.
__global__ __launch_bounds__(256, 3) void vq_mfma(const u16* __restrict__ zb,
                                                  const u16* __restrict__ cbb,
                                                  int* __restrict__ cand_cnt,
                                                  u64* __restrict__ candkey) {
    __shared__ u16   Xs[ROWS_B * DIM];        // 32 KB
    __shared__ float lcd[ROWS_B * LSLOTS];    // 6 KB
    __shared__ int   lci[ROWS_B * LSLOTS];    // 6 KB
    __shared__ int   lcnt[ROWS_B];
    __shared__ float gmaxw[4][ROWS_B];        // per-wave row maxes

    const int tid   = threadIdx.x;
    const int lane  = tid & 63;
    const int wave  = tid >> 6;
    const int quad  = lane >> 4;
    const int l16   = lane & 15;
    const int split = blockIdx.x;
    const int n0    = blockIdx.y * ROWS_B;

    if (tid < ROWS_B) lcnt[tid] = 0;

    // ---- stage X once: 2048 16B-units, 64 units/instr, 8 instr/wave
#pragma unroll
    for (int t = 0; t < 8; t++) {
        int ubase = wave * 512 + t * 64;
        int u     = ubase + lane;
        int row   = u >> 5;
        int p     = u & 31;
        int csrc  = p ^ (row & 7);
        gld16(&Xs[ubase * 8], zb + (size_t)(n0 + row) * DIM + csrc * 8);
    }
    __syncthreads();   // vmcnt drained; Xs valid for all; lcnt init visible

    float runmax[4][4];          // [row-tile i][reg r], thread-local
#pragma unroll
    for (int i = 0; i < 4; i++)
#pragma unroll
        for (int r = 0; r < 4; r++) runmax[i][r] = -3.0e38f;

    for (int kt = 0; kt < KS / KT_CODES; kt++) {
        const int kw = split * KS + kt * KT_CODES + wave * 64;  // wave's code base
        f32x4 acc[4][4];
#pragma unroll
        for (int i = 0; i < 4; i++)
#pragma unroll
            for (int j = 0; j < 4; j++)
#pragma unroll
                for (int e = 0; e < 4; e++) acc[i][j][e] = 0.0f;

#pragma unroll
        for (int ks = 0; ks < 8; ks++) {
            s16x8 af[4], bfr[4];
#pragma unroll
            for (int i = 0; i < 4; i++)
                af[i] = *(const s16x8*)&Xs[(i * 16 + l16) * DIM +
                                           (((ks << 2) | quad) ^ (l16 & 7)) * 8];
#pragma unroll
            for (int j = 0; j < 4; j++)
                bfr[j] = *(const s16x8*)(cbb + (size_t)(kw + j * 16 + l16) * DIM +
                                         ks * 32 + quad * 8);
#pragma unroll
            for (int i = 0; i < 4; i++)
#pragma unroll
                for (int j = 0; j < 4; j++)
                    acc[i][j] = __builtin_amdgcn_mfma_f32_16x16x32_bf16(af[i], bfr[j], acc[i][j], 0, 0, 0);
        }

        // ---- epilogue (no barriers): local-threshold margin appends
#pragma unroll
        for (int i = 0; i < 4; i++)
#pragma unroll
            for (int r = 0; r < 4; r++) {
                float mj = fmaxf(fmaxf(acc[i][0][r], acc[i][1][r]),
                                 fmaxf(acc[i][2][r], acc[i][3][r]));
                if (kt == 0) {
                    // seed: shared max over the wave's 64 codes (4 shfl)
                    float m = mj;
                    m = fmaxf(m, __shfl_xor(m, 1, 64));
                    m = fmaxf(m, __shfl_xor(m, 2, 64));
                    m = fmaxf(m, __shfl_xor(m, 4, 64));
                    m = fmaxf(m, __shfl_xor(m, 8, 64));
                    runmax[i][r] = m;
                }
                float thr = runmax[i][r] - MARGIN_ACC;
                if (mj >= thr) {               // rare past kt0
                    int rl = i * 16 + quad * 4 + r;
#pragma unroll
                    for (int j = 0; j < 4; j++) {
                        float d = acc[i][j][r];
                        if (d >= thr) {
                            int pos = atomicAdd(&lcnt[rl], 1);
                            if (pos < LSLOTS) {
                                lcd[rl * LSLOTS + pos] = d;
                                lci[rl * LSLOTS + pos] = kw + j * 16 + l16;
                            }
                        }
                    }
                }
                runmax[i][r] = fmaxf(runmax[i][r], mj);
            }
    }

    // per-wave row maxes -> LDS
#pragma unroll
    for (int i = 0; i < 4; i++)
#pragma unroll
        for (int r = 0; r < 4; r++) {
            float m = runmax[i][r];
            m = fmaxf(m, __shfl_xor(m, 1, 64));
            m = fmaxf(m, __shfl_xor(m, 2, 64));
            m = fmaxf(m, __shfl_xor(m, 4, 64));
            m = fmaxf(m, __shfl_xor(m, 8, 64));
            if (l16 == 0) gmaxw[wave][i * 16 + quad * 4 + r] = m;
        }
    __syncthreads();

    // final filter: keep appends within margin of the row's split max
    if (tid < ROWS_B) {
        int   row  = tid, n = n0 + row;
        int   raw  = lcnt[row];
        int   cnt  = raw < LSLOTS ? raw : LSLOTS;
        float rmax = fmaxf(fmaxf(gmaxw[0][row], gmaxw[1][row]),
                           fmaxf(gmaxw[2][row], gmaxw[3][row]));
        float thr  = rmax - MARGIN_ACC;
        int   base = (n * SPLITK + split) * GSLOTS;
        int   w = 0, kept = 0;
        for (int s = 0; s < cnt; s++) {
            if (lcd[row * LSLOTS + s] >= thr) {
                kept++;
                if (w < GSLOTS) {
                    float d = lcd[row * LSLOTS + s];
                    candkey[base + w] = ((u64)__float_as_uint(d) << 32)
                                        | (unsigned)lci[row * LSLOTS + s];
                    w++;
                }
            }
        }
        // overflow (appends dropped or survivors truncated) -> exact-rescan flag
        cand_cnt[n * SPLITK + split] = (raw > LSLOTS || kept > GSLOTS) ? -1 : w;
    }
}

// ---------------------------------------------------------------- kernel C
// Global prune (max dot over all 64 stored candidates - margin) -> ~1.35
// survivors/row; exact fp32 recheck with the R2-proven association;
// lexicographic (dist,idx) min; gather + z_q_st + rowloss. One wave per row.
__global__ __launch_bounds__(256) void vq_finalize(const float* __restrict__ z_e,
                                                   const float* __restrict__ cb,
                                                   const float* __restrict__ xnorm,
                                                   const float* __restrict__ cnorm,
                                                   const int* __restrict__ cand_cnt,
                                                   const u64* __restrict__ candkey,
                                                   float* __restrict__ out_zq,
                                                   float* __restrict__ out_idx,
                                                   float* __restrict__ rowloss) {
    const int n    = blockIdx.x * 4 + (threadIdx.x >> 6);
    const int lane = threadIdx.x & 63;
    const int s    = lane >> 3;          // split of my slot
    const int t    = lane & 7;           // slot within split

    const float* xr = z_e + (size_t)n * DIM;
    const float  xn = xnorm[n];

    int  cnt   = cand_cnt[n * SPLITK + s];
    u64  ck    = candkey[(size_t)n * 64 + lane];
    bool valid = (cnt >= 0) && (t < cnt);
    float dot  = valid ? __uint_as_float((unsigned)(ck >> 32)) : -3.0e38f;

    float gmax = dot;
#pragma unroll
    for (int off = 1; off < 64; off <<= 1)
        gmax = fmaxf(gmax, __shfl_xor(gmax, off, 64));
    float thr = gmax - MARGIN_ACC;

    u64 key = ~0ULL;
    if (valid && dot >= thr) {
        int  idx  = (int)(unsigned)(ck & 0xffffffffu);
        float m   = exact_dot(xr, cb + (size_t)idx * DIM);
        float dist = __builtin_fmaf(-2.0f, m, xn) + cnorm[idx];
        key = ((u64)__float_as_uint(dist) << 32) | (unsigned)idx;
    }

    // overflow fallback: exact rescan of flagged splits (~never taken)
#pragma unroll
    for (int fs = 0; fs < SPLITK; fs++) {
        if (__builtin_expect(cand_cnt[n * SPLITK + fs] < 0, 0)) {
            for (int it = 0; it < KS / 64; it++) {
                int k = fs * KS + it * 64 + lane;
                float m    = exact_dot(xr, cb + (size_t)k * DIM);
                float dist = __builtin_fmaf(-2.0f, m, xn) + cnorm[k];
                key = u64min(key, ((u64)__float_as_uint(dist) << 32) | (unsigned)k);
            }
        }
    }

#pragma unroll
    for (int off = 1; off < 64; off <<= 1)
        key = u64min(key, __shfl_xor(key, off, 64));

    int idx = (int)(unsigned)(key & 0xffffffffu);
    if (key == ~0ULL) idx = 0;  // unreachable safety

    float4 x = *(const float4*)(xr + lane * 4);
    float4 c = *(const float4*)(cb + (size_t)idx * DIM + lane * 4);
    float4 st;
    st.x = x.x + (c.x - x.x); st.y = x.y + (c.y - x.y);
    st.z = x.z + (c.z - x.z); st.w = x.w + (c.w - x.w);
    *(float4*)(out_zq + (size_t)n * DIM + lane * 4) = st;

    float d0 = x.x - c.x, d1 = x.y - c.y, d2 = x.z - c.z, d3 = x.w - c.w;
    float s2 = (d0 * d0 + d1 * d1) + (d2 * d2 + d3 * d3);
#pragma unroll
    for (int off = 1; off < 64; off <<= 1)
        s2 += __shfl_xor(s2, off, 64);
    if (lane == 0) {
        rowloss[n] = s2;
        out_idx[n] = (float)idx;
    }
}

// ---------------------------------------------------------------- kernel D
__global__ __launch_bounds__(256) void vq_loss(const float* __restrict__ rowloss,
                                               float* __restrict__ out_loss) {
    __shared__ double sd[256];
    double s = 0.0;
    for (int i = threadIdx.x; i < N_ROWS; i += 256) s += (double)rowloss[i];
    sd[threadIdx.x] = s;
    __syncthreads();
    for (int off = 128; off; off >>= 1) {
        if (threadIdx.x < off) sd[threadIdx.x] += sd[threadIdx.x + off];
        __syncthreads();
    }
    if (threadIdx.x == 0) {
        double mean = sd[0] / (double)((size_t)N_ROWS * DIM);
        out_loss[0] = (float)(1.25 * mean);
    }
}

// ---------------------------------------------------------------- launch
extern "C" void kernel_launch(void* const* d_in, const int* in_sizes, int n_in,
                              void* d_out, int out_size, void* d_ws, size_t ws_size,
                              hipStream_t stream) {
    const float* z_e = (const float*)d_in[0];
    const float* cb  = (const float*)d_in[1];

    float* out   = (float*)d_out;
    float* zq    = out;
    float* oidx  = out + (size_t)N_ROWS * DIM;
    float* oloss = oidx + N_ROWS;

    // ws (~12.5 MB): zb 4MB | cbb 4MB | xnorm | cnorm | rowloss | cand_cnt 256KB | candkey 4MB
    u16*   zb       = (u16*)d_ws;
    u16*   cbb      = zb + (size_t)N_ROWS * DIM;
    float* xnorm    = (float*)(cbb + (size_t)K_CODES * DIM);
    float* cnorm    = xnorm + N_ROWS;
    float* rowloss  = cnorm + K_CODES;
    int*   cand_cnt = (int*)(rowloss + N_ROWS);
    u64*   candkey  = (u64*)(cand_cnt + N_ROWS * SPLITK);

    vq_prep    <<<(N_ROWS + K_CODES) / 4, 256, 0, stream>>>(z_e, cb, zb, cbb, xnorm, cnorm);
    // blockIdx.x = split -> linear%8 pins each split to one XCD (L2-resident 0.5MB)
    vq_mfma    <<<dim3(SPLITK, N_ROWS / ROWS_B), 256, 0, stream>>>(zb, cbb, cand_cnt, candkey);
    vq_finalize<<<N_ROWS / 4, 256, 0, stream>>>(z_e, cb, xnorm, cnorm, cand_cnt, candkey, zq, oidx, rowloss);
    vq_loss    <<<1, 256, 0, stream>>>(rowloss, oloss);
}

// Round 6
// 200.947 us; speedup vs baseline: 16.8720x; 16.8720x over previous
//
#include <hip/hip_runtime.h>
#include <stdint.h>

#define N_ROWS  8192   // B*S = 4*2048
#define DIM     256
#define K_CODES 8192
#define SPLITK  8
#define KS      1024          // codes per split
#define ROWS_B  64            // rows per block
#define KT_CODES 256          // codes per kt iteration (64 per wave)
#define LSLOTS  32            // per-row append slots in LDS (mean ~3 w/ shared thr)
#define GSLOTS  8             // per-row-split survivor slots (64/row = 1 u64/lane)
// acc(dot) margin >= dist-grid tie window (~3.3e-5) + 2*bf16 dot err max (~4e-5)
#define MARGIN_ACC 1.0e-4f

typedef unsigned long long u64;
typedef unsigned short u16;
typedef short s16x8 __attribute__((ext_vector_type(8)));   // 8 bf16 = 4 VGPR
typedef float f32x4 __attribute__((ext_vector_type(4)));

__device__ __forceinline__ u64 u64min(u64 a, u64 b) { return a < b ? a : b; }

__device__ __forceinline__ u16 f2bf(float f) {   // RNE, no NaNs here
    unsigned u = __float_as_uint(f);
    u += 0x7fffu + ((u >> 16) & 1u);
    return (u16)(u >> 16);
}

// monotone float<->uint (works for negatives): order(f) == order(fkey(f))
__device__ __forceinline__ unsigned fkey(float f) {
    unsigned b = __float_as_uint(f);
    return (b & 0x80000000u) ? ~b : (b | 0x80000000u);
}
__device__ __forceinline__ float funkey(unsigned k) {
    unsigned b = (k & 0x80000000u) ? (k ^ 0x80000000u) : ~k;
    return __uint_as_float(b);
}

__device__ __forceinline__ void gld16(void* lds, const void* g) {
    __builtin_amdgcn_global_load_lds(
        (const __attribute__((address_space(1))) unsigned int*)g,
        (__attribute__((address_space(3))) unsigned int*)lds, 16, 0, 0);
}

// exact fp32 dot, ascending-d association (R2-proven, absmax 0), float4 loads
__device__ __forceinline__ float exact_dot(const float* __restrict__ xr,
                                           const float* __restrict__ cr) {
    const float4* x4 = (const float4*)xr;
    const float4* c4 = (const float4*)cr;
    float acc = 0.0f;
#pragma unroll 8
    for (int c = 0; c < DIM / 4; c++) {
        float4 xv = x4[c], cv = c4[c];
        acc = __builtin_fmaf(xv.x, cv.x, acc);
        acc = __builtin_fmaf(xv.y, cv.y, acc);
        acc = __builtin_fmaf(xv.z, cv.z, acc);
        acc = __builtin_fmaf(xv.w, cv.w, acc);
    }
    return acc;
}

// ---------------------------------------------------------------- kernel A
// Fused: bf16 conversion of z_e & cb + row norms. One wave per row.
__global__ __launch_bounds__(256) void vq_prep(const float* __restrict__ z_e,
                                               const float* __restrict__ cb,
                                               u16* __restrict__ zb,
                                               u16* __restrict__ cbb,
                                               float* __restrict__ xnorm,
                                               float* __restrict__ cnorm) {
    int wid  = (blockIdx.x * 256 + threadIdx.x) >> 6;
    int lane = threadIdx.x & 63;
    const float* src; u16* d16; float* dn;
    if (wid < N_ROWS) { src = z_e + (size_t)wid * DIM; d16 = zb + (size_t)wid * DIM; dn = xnorm + wid; }
    else              { int k = wid - N_ROWS;
                        src = cb  + (size_t)k   * DIM; d16 = cbb + (size_t)k * DIM; dn = cnorm + k; }
    float4 v = *(const float4*)(src + lane * 4);
    ushort4 h;
    h.x = f2bf(v.x); h.y = f2bf(v.y); h.z = f2bf(v.z); h.w = f2bf(v.w);
    *(ushort4*)(d16 + lane * 4) = h;
    float s = (v.x * v.x + v.y * v.y) + (v.z * v.z + v.w * v.w);
#pragma unroll
    for (int off = 1; off < 64; off <<= 1)
        s += __shfl_xor(s, off, 64);
    if (lane == 0) *dn = s;
}

// ---------------------------------------------------------------- kernel B
// Barrier-free-K-loop MFMA dot GEMM + margin-candidate emission.
// Block = 64 rows x 1024 codes (one split). X-tile LDS-resident (32 KB,
// XOR-swizzled 16B chunks -> ds_read_b128 2-way = free). B-frags per-lane
// from global (L2-resident split): no K-loop barriers.
// Shared per-row threshold: LDS atomicMax of fkey(wave tile max) each kt
// (DS wave-ordered; racy cross-wave reads only loosen -> still a superset).
__global__ __launch_bounds__(256, 3) void vq_mfma(const u16* __restrict__ zb,
                                                  const u16* __restrict__ cbb,
                                                  int* __restrict__ cand_cnt,
                                                  u64* __restrict__ candkey) {
    __shared__ u16      Xs[ROWS_B * DIM];        // 32 KB
    __shared__ float    lcd[ROWS_B * LSLOTS];    // 8 KB
    __shared__ int      lci[ROWS_B * LSLOTS];    // 8 KB
    __shared__ int      lcnt[ROWS_B];
    __shared__ unsigned smax[ROWS_B];            // fkey-encoded row max

    const int tid   = threadIdx.x;
    const int lane  = tid & 63;
    const int wave  = tid >> 6;
    const int quad  = lane >> 4;
    const int l16   = lane & 15;
    const int split = blockIdx.x;
    const int n0    = blockIdx.y * ROWS_B;

    if (tid < ROWS_B) { lcnt[tid] = 0; smax[tid] = 0u; }

    // ---- stage X once: 2048 16B-units, 64 units/instr, 8 instr/wave
#pragma unroll
    for (int t = 0; t < 8; t++) {
        int ubase = wave * 512 + t * 64;
        int u     = ubase + lane;
        int row   = u >> 5;
        int p     = u & 31;
        int csrc  = p ^ (row & 7);
        gld16(&Xs[ubase * 8], zb + (size_t)(n0 + row) * DIM + csrc * 8);
    }
    __syncthreads();   // vmcnt drained; Xs/lcnt/smax init visible

    for (int kt = 0; kt < KS / KT_CODES; kt++) {
        const int kw = split * KS + kt * KT_CODES + wave * 64;  // wave's code base
        f32x4 acc[4][4];
#pragma unroll
        for (int i = 0; i < 4; i++)
#pragma unroll
            for (int j = 0; j < 4; j++)
#pragma unroll
                for (int e = 0; e < 4; e++) acc[i][j][e] = 0.0f;

#pragma unroll
        for (int ks = 0; ks < 8; ks++) {
            s16x8 af[4], bfr[4];
#pragma unroll
            for (int i = 0; i < 4; i++)
                af[i] = *(const s16x8*)&Xs[(i * 16 + l16) * DIM +
                                           (((ks << 2) | quad) ^ (l16 & 7)) * 8];
#pragma unroll
            for (int j = 0; j < 4; j++)
                bfr[j] = *(const s16x8*)(cbb + (size_t)(kw + j * 16 + l16) * DIM +
                                         ks * 32 + quad * 8);
#pragma unroll
            for (int i = 0; i < 4; i++)
#pragma unroll
                for (int j = 0; j < 4; j++)
                    acc[i][j] = __builtin_amdgcn_mfma_f32_16x16x32_bf16(af[i], bfr[j], acc[i][j], 0, 0, 0);
        }

        // ---- epilogue (no barriers): shared-threshold margin appends
#pragma unroll
        for (int i = 0; i < 4; i++)
#pragma unroll
            for (int r = 0; r < 4; r++) {
                int rl = i * 16 + quad * 4 + r;
                // wave-level max over this tile's 64 codes for this row
                float m = fmaxf(fmaxf(acc[i][0][r], acc[i][1][r]),
                                fmaxf(acc[i][2][r], acc[i][3][r]));
                m = fmaxf(m, __shfl_xor(m, 1, 64));
                m = fmaxf(m, __shfl_xor(m, 2, 64));
                m = fmaxf(m, __shfl_xor(m, 4, 64));
                m = fmaxf(m, __shfl_xor(m, 8, 64));
                if (l16 == 0) atomicMax(&smax[rl], fkey(m));
                // thr: global-so-far (racy read, conservative) merged with own m
                float g   = funkey(smax[rl]);
                float thr = fmaxf(g, m) - MARGIN_ACC;
                float mj = fmaxf(fmaxf(acc[i][0][r], acc[i][1][r]),
                                 fmaxf(acc[i][2][r], acc[i][3][r]));
                if (mj >= thr) {               // rare: ~5% of lanes
#pragma unroll
                    for (int j = 0; j < 4; j++) {
                        float d = acc[i][j][r];
                        if (d >= thr) {
                            int pos = atomicAdd(&lcnt[rl], 1);
                            if (pos < LSLOTS) {
                                lcd[rl * LSLOTS + pos] = d;
                                lci[rl * LSLOTS + pos] = kw + j * 16 + l16;
                            }
                        }
                    }
                }
            }
    }

    __syncthreads();   // all appends + smax finals visible

    // final filter: keep appends within margin of the row's split max
    if (tid < ROWS_B) {
        int   row  = tid, n = n0 + row;
        int   raw  = lcnt[row];
        int   cnt  = raw < LSLOTS ? raw : LSLOTS;
        float thr  = funkey(smax[row]) - MARGIN_ACC;
        int   base = (n * SPLITK + split) * GSLOTS;
        int   w = 0, kept = 0;
        for (int s = 0; s < cnt; s++) {
            if (lcd[row * LSLOTS + s] >= thr) {
                kept++;
                if (w < GSLOTS) {
                    float d = lcd[row * LSLOTS + s];
                    candkey[base + w] = ((u64)__float_as_uint(d) << 32)
                                        | (unsigned)lci[row * LSLOTS + s];
                    w++;
                }
            }
        }
        // overflow (appends dropped or survivors truncated) -> exact-rescan flag
        cand_cnt[n * SPLITK + split] = (raw > LSLOTS || kept > GSLOTS) ? -1 : w;
    }
}

// ---------------------------------------------------------------- kernel C
// Global prune (max stored dot - margin) -> ~1.5 survivors/row; exact fp32
// recheck (ascending-d association); lexicographic (dist,idx) min; gather +
// z_q_st + rowloss. One wave per row.
__global__ __launch_bounds__(256) void vq_finalize(const float* __restrict__ z_e,
                                                   const float* __restrict__ cb,
                                                   const float* __restrict__ xnorm,
                                                   const float* __restrict__ cnorm,
                                                   const int* __restrict__ cand_cnt,
                                                   const u64* __restrict__ candkey,
                                                   float* __restrict__ out_zq,
                                                   float* __restrict__ out_idx,
                                                   float* __restrict__ rowloss) {
    const int n    = blockIdx.x * 4 + (threadIdx.x >> 6);
    const int lane = threadIdx.x & 63;
    const int s    = lane >> 3;          // split of my slot
    const int t    = lane & 7;           // slot within split

    const float* xr = z_e + (size_t)n * DIM;
    const float  xn = xnorm[n];

    int  cnt   = cand_cnt[n * SPLITK + s];
    u64  ck    = candkey[(size_t)n * 64 + lane];
    bool valid = (cnt >= 0) && (t < cnt);
    float dot  = valid ? __uint_as_float((unsigned)(ck >> 32)) : -3.0e38f;

    float gmax = dot;
#pragma unroll
    for (int off = 1; off < 64; off <<= 1)
        gmax = fmaxf(gmax, __shfl_xor(gmax, off, 64));
    float thr = gmax - MARGIN_ACC;

    u64 key = ~0ULL;
    if (valid && dot >= thr) {
        int  idx   = (int)(unsigned)(ck & 0xffffffffu);
        float m    = exact_dot(xr, cb + (size_t)idx * DIM);
        float dist = __builtin_fmaf(-2.0f, m, xn) + cnorm[idx];
        key = ((u64)__float_as_uint(dist) << 32) | (unsigned)idx;
    }

    // overflow fallback: exact rescan of flagged splits (p ~ 0 now)
#pragma unroll
    for (int fs = 0; fs < SPLITK; fs++) {
        if (__builtin_expect(cand_cnt[n * SPLITK + fs] < 0, 0)) {
            for (int it = 0; it < KS / 64; it++) {
                int k = fs * KS + it * 64 + lane;
                float m    = exact_dot(xr, cb + (size_t)k * DIM);
                float dist = __builtin_fmaf(-2.0f, m, xn) + cnorm[k];
                key = u64min(key, ((u64)__float_as_uint(dist) << 32) | (unsigned)k);
            }
        }
    }

#pragma unroll
    for (int off = 1; off < 64; off <<= 1)
        key = u64min(key, __shfl_xor(key, off, 64));

    int idx = (int)(unsigned)(key & 0xffffffffu);
    if (key == ~0ULL) idx = 0;  // unreachable safety

    float4 x = *(const float4*)(xr + lane * 4);
    float4 c = *(const float4*)(cb + (size_t)idx * DIM + lane * 4);
    float4 st;
    st.x = x.x + (c.x - x.x); st.y = x.y + (c.y - x.y);
    st.z = x.z + (c.z - x.z); st.w = x.w + (c.w - x.w);
    *(float4*)(out_zq + (size_t)n * DIM + lane * 4) = st;

    float d0 = x.x - c.x, d1 = x.y - c.y, d2 = x.z - c.z, d3 = x.w - c.w;
    float s2 = (d0 * d0 + d1 * d1) + (d2 * d2 + d3 * d3);
#pragma unroll
    for (int off = 1; off < 64; off <<= 1)
        s2 += __shfl_xor(s2, off, 64);
    if (lane == 0) {
        rowloss[n] = s2;
        out_idx[n] = (float)idx;
    }
}

// ---------------------------------------------------------------- kernel D
__global__ __launch_bounds__(256) void vq_loss(const float* __restrict__ rowloss,
                                               float* __restrict__ out_loss) {
    __shared__ double sd[256];
    double s = 0.0;
    for (int i = threadIdx.x; i < N_ROWS; i += 256) s += (double)rowloss[i];
    sd[threadIdx.x] = s;
    __syncthreads();
    for (int off = 128; off; off >>= 1) {
        if (threadIdx.x < off) sd[threadIdx.x] += sd[threadIdx.x + off];
        __syncthreads();
    }
    if (threadIdx.x == 0) {
        double mean = sd[0] / (double)((size_t)N_ROWS * DIM);
        out_loss[0] = (float)(1.25 * mean);
    }
}

// ---------------------------------------------------------------- launch
extern "C" void kernel_launch(void* const* d_in, const int* in_sizes, int n_in,
                              void* d_out, int out_size, void* d_ws, size_t ws_size,
                              hipStream_t stream) {
    const float* z_e = (const float*)d_in[0];
    const float* cb  = (const float*)d_in[1];

    float* out   = (float*)d_out;
    float* zq    = out;
    float* oidx  = out + (size_t)N_ROWS * DIM;
    float* oloss = oidx + N_ROWS;

    // ws (~12.5 MB): zb 4MB | cbb 4MB | xnorm | cnorm | rowloss | cand_cnt 256KB | candkey 4MB
    u16*   zb       = (u16*)d_ws;
    u16*   cbb      = zb + (size_t)N_ROWS * DIM;
    float* xnorm    = (float*)(cbb + (size_t)K_CODES * DIM);
    float* cnorm    = xnorm + N_ROWS;
    float* rowloss  = cnorm + K_CODES;
    int*   cand_cnt = (int*)(rowloss + N_ROWS);
    u64*   candkey  = (u64*)(cand_cnt + N_ROWS * SPLITK);

    vq_prep    <<<(N_ROWS + K_CODES) / 4, 256, 0, stream>>>(z_e, cb, zb, cbb, xnorm, cnorm);
    // blockIdx.x = split -> linear%8 pins each split to one XCD (L2-resident 0.5MB)
    vq_mfma    <<<dim3(SPLITK, N_ROWS / ROWS_B), 256, 0, stream>>>(zb, cbb, cand_cnt, candkey);
    vq_finalize<<<N_ROWS / 4, 256, 0, stream>>>(z_e, cb, xnorm, cnorm, cand_cnt, candkey, zq, oidx, rowloss);
    vq_loss    <<<1, 256, 0, stream>>>(rowloss, oloss);
}